// Round 6
// baseline (381.409 us; speedup 1.0000x reference)
//
#include <hip/hip_runtime.h>
#include <math.h>

#define N 8192
#define C 10
#define NUM_ITERS 5
#define CBLOCK 64         /* combine block size */
#define FBLOCK 256        /* filter block: 4 waves */
#define JCH 8             /* j splits (partial accumulators) */
#define JPB (N / JCH)     /* 1024 j's per block */
#define JT 512            /* j's staged per LDS chunk */
#define IBLK 128          /* i's per filter block: 4 waves x 32 */
#define NIB (N / IBLK)    /* 64 */
#define LOG2E 1.44269504088896340736f
#define C3 (LOG2E / 64.0f)
#define PROW (JT + 8)     /* padded LDS row for p (f16 elems) */

typedef _Float16 half8 __attribute__((ext_vector_type(8)));
typedef _Float16 half4 __attribute__((ext_vector_type(4)));
typedef float f32x4 __attribute__((ext_vector_type(4)));

// ws byte offsets:
//   ajs half8[N] : j-side spatial aug features   [f*C3 x3, 0, 0,0,-h3*C3, 1]
//   ajb half8[N] : j-side bilateral aug features [f*L2E x6, -h6*L2E, 1]
//   pf  f16[16][N] : softmax probs, rows 10..15 zero
//   part float[JCH][20][N] : per-j-split partials, rows 0-9 spatial, 10-19 bilateral
#define WS_AJS 0
#define WS_AJB (N * 16)
#define WS_PF  (N * 32)
#define WS_PART (N * 64)

// do_filter=0: q=unaries, build ajs/ajb (prep fused).
// is_last=1: write q to out (skip softmax).
__global__ __launch_bounds__(CBLOCK) void combine_kernel(
    const float* __restrict__ unaries, const float* __restrict__ feat,
    const float* __restrict__ SW, const float* __restrict__ BW,
    const float* __restrict__ CM, const float* __restrict__ part,
    _Float16* __restrict__ pf, half8* __restrict__ ajs, half8* __restrict__ ajb,
    float* __restrict__ out, int do_filter, int is_last) {
    __shared__ float sSW[100], sBW[100], sCM[100];
    int t = threadIdx.x;
    for (int k = t; k < 100; k += CBLOCK) { sSW[k] = SW[k]; sBW[k] = BW[k]; sCM[k] = CM[k]; }
    __syncthreads();
    int n = blockIdx.x * CBLOCK + t;

    float q[C];
    if (do_filter) {
        float sp[C], bl[C];
#pragma unroll
        for (int k = 0; k < C; ++k) { sp[k] = 0.0f; bl[k] = 0.0f; }
        for (int jc = 0; jc < JCH; ++jc) {
            const float* pp = part + (size_t)jc * 20 * N + n;
#pragma unroll
            for (int k = 0; k < C; ++k) {
                sp[k] += pp[k * N];
                bl[k] += pp[(C + k) * N];
            }
        }
        float msg[C];
#pragma unroll
        for (int c = 0; c < C; ++c) {
            float m = 0.0f;
#pragma unroll
            for (int k = 0; k < C; ++k)
                m += sSW[c * C + k] * sp[k] + sBW[c * C + k] * bl[k];
            msg[c] = m;
        }
#pragma unroll
        for (int c = 0; c < C; ++c) {
            float pw = 0.0f;
#pragma unroll
            for (int k = 0; k < C; ++k) pw += sCM[c * C + k] * msg[k];
            q[c] = unaries[c * N + n] - pw;
        }
    } else {
#pragma unroll
        for (int c = 0; c < C; ++c) q[c] = unaries[c * N + n];
        // prep: augmented j-side feature vectors
        float f[6];
#pragma unroll
        for (int d = 0; d < 6; ++d) f[d] = feat[d * N + n];
        float h3 = 0.5f * (f[0] * f[0] + f[1] * f[1] + f[2] * f[2]);
        float h6 = h3 + 0.5f * (f[3] * f[3] + f[4] * f[4] + f[5] * f[5]);
        half8 a = {};
        a[0] = (_Float16)(f[0] * C3);
        a[1] = (_Float16)(f[1] * C3);
        a[2] = (_Float16)(f[2] * C3);
        a[6] = (_Float16)(-h3 * C3);
        a[7] = (_Float16)1.0f;
        ajs[n] = a;
        half8 b;
#pragma unroll
        for (int d = 0; d < 6; ++d) b[d] = (_Float16)(f[d] * LOG2E);
        b[6] = (_Float16)(-h6 * LOG2E);
        b[7] = (_Float16)1.0f;
        ajb[n] = b;
    }

    if (is_last) {
#pragma unroll
        for (int c = 0; c < C; ++c) out[c * N + n] = q[c];
    } else {
        float m = q[0];
#pragma unroll
        for (int c = 1; c < C; ++c) m = fmaxf(m, q[c]);
        float e[C], s = 0.0f;
#pragma unroll
        for (int c = 0; c < C; ++c) {
            e[c] = __builtin_amdgcn_exp2f((q[c] - m) * LOG2E);
            s += e[c];
        }
        float inv = 1.0f / s;
#pragma unroll
        for (int c = 0; c < C; ++c) pf[c * N + n] = (_Float16)(e[c] * inv);
#pragma unroll
        for (int c = C; c < 16; ++c) pf[c * N + n] = (_Float16)0.0f;
    }
}

static __device__ inline half4 expcvt(f32x4 d) {
    half4 r;
    r[0] = (_Float16)__builtin_amdgcn_exp2f(d[0]);
    r[1] = (_Float16)__builtin_amdgcn_exp2f(d[1]);
    r[2] = (_Float16)__builtin_amdgcn_exp2f(d[2]);
    r[3] = (_Float16)__builtin_amdgcn_exp2f(d[3]);
    return r;
}

__global__ __launch_bounds__(FBLOCK, 4) void filter_kernel(
    const float* __restrict__ feat, const half4* __restrict__ ajs,
    const half4* __restrict__ ajb, const _Float16* __restrict__ pf,
    float* __restrict__ part) {
    __shared__ half4 ajs_l[JT * 2];        //  8 KB  [j][h]
    __shared__ half4 ajb_l[JT * 2];        //  8 KB
    __shared__ _Float16 p_l[16 * PROW];    // 16.25 KB

    int t = threadIdx.x;
    int ibb = blockIdx.x * IBLK;
    int jc = blockIdx.y;

    int lane = t & 63;
    int w = t >> 6;
    int il = lane & 15;
    int quad = lane >> 4;
    int h = quad & 1;
    bool klo = (quad < 2);
    int i0 = ibb + w * 32;   // wave's 32 i's: subtile0 = i0.., subtile1 = i0+16..

    const half4 hz = {};

    // B1 fragments (i-side aug), K=16 layout: lane holds B[k=quad*4+r][n=il]
    half4 b1s0, b1s1, b1b0, b1b1;
#pragma unroll
    for (int s = 0; s < 2; ++s) {
        int i = i0 + s * 16 + il;
        float g0 = feat[0 * N + i], g1 = feat[1 * N + i], g2 = feat[2 * N + i];
        float g3 = feat[3 * N + i], g4 = feat[4 * N + i], g5 = feat[5 * N + i];
        float h3 = 0.5f * (g0 * g0 + g1 * g1 + g2 * g2);
        float h6 = h3 + 0.5f * (g3 * g3 + g4 * g4 + g5 * g5);
        half4 slo = {(_Float16)g0, (_Float16)g1, (_Float16)g2, (_Float16)0.0f};
        half4 shi = {(_Float16)0.0f, (_Float16)0.0f, (_Float16)1.0f, (_Float16)(-h3 * C3)};
        half4 blo = {(_Float16)g0, (_Float16)g1, (_Float16)g2, (_Float16)g3};
        half4 bhi = {(_Float16)g4, (_Float16)g5, (_Float16)1.0f, (_Float16)(-h6 * LOG2E)};
        half4 vs = klo ? (h ? shi : slo) : hz;
        half4 vb = klo ? (h ? bhi : blo) : hz;
        if (s == 0) { b1s0 = vs; b1b0 = vb; } else { b1s1 = vs; b1b1 = vb; }
    }

    f32x4 as0 = {0.f, 0.f, 0.f, 0.f}, as1 = {0.f, 0.f, 0.f, 0.f};
    f32x4 ab0 = {0.f, 0.f, 0.f, 0.f}, ab1 = {0.f, 0.f, 0.f, 0.f};
    const f32x4 zero = {0.f, 0.f, 0.f, 0.f};

    for (int ch = 0; ch < JPB / JT; ++ch) {
        int jbase = jc * JPB + ch * JT;
        // ---- stage j-chunk (coalesced float4) ----
        {
            const float4* s0 = (const float4*)(ajs + (size_t)jbase * 2);
            const float4* s1 = (const float4*)(ajb + (size_t)jbase * 2);
            float4* d0 = (float4*)ajs_l;
            float4* d1 = (float4*)ajb_l;
            for (int k = t; k < JT; k += FBLOCK) { d0[k] = s0[k]; d1[k] = s1[k]; }
            const float4* ps = (const float4*)pf;
            float4* pd = (float4*)p_l;
            for (int k = t; k < 16 * (JT / 8); k += FBLOCK) {
                int c = k >> 6, off = k & 63;
                pd[c * (PROW / 8) + off] = ps[c * (N / 8) + (jbase >> 3) + off];
            }
        }
        __syncthreads();

#pragma unroll 2
        for (int jb = 0; jb < JT; jb += 32) {
            int j0 = jb, j1 = jb + 16;
            // hoisted LDS reads (both groups) so latency overlaps
            half4 vs0 = ajs_l[(j0 + il) * 2 + h];
            half4 vb0 = ajb_l[(j0 + il) * 2 + h];
            half4 vs1 = ajs_l[(j1 + il) * 2 + h];
            half4 vb1 = ajb_l[(j1 + il) * 2 + h];
            half4 p2_0 = *(const half4*)&p_l[il * PROW + j0 + quad * 4];
            half4 p2_1 = *(const half4*)&p_l[il * PROW + j1 + quad * 4];
            half4 a1s_0 = klo ? vs0 : hz;
            half4 a1b_0 = klo ? vb0 : hz;
            half4 a1s_1 = klo ? vs1 : hz;
            half4 a1b_1 = klo ? vb1 : hz;

            // GEMM-1: S^T[j][i] in C/D layout (8 independent chains)
            f32x4 d0 = __builtin_amdgcn_mfma_f32_16x16x16f16(a1s_0, b1s0, zero, 0, 0, 0);
            f32x4 d1 = __builtin_amdgcn_mfma_f32_16x16x16f16(a1s_0, b1s1, zero, 0, 0, 0);
            f32x4 d2 = __builtin_amdgcn_mfma_f32_16x16x16f16(a1b_0, b1b0, zero, 0, 0, 0);
            f32x4 d3 = __builtin_amdgcn_mfma_f32_16x16x16f16(a1b_0, b1b1, zero, 0, 0, 0);
            f32x4 d4 = __builtin_amdgcn_mfma_f32_16x16x16f16(a1s_1, b1s0, zero, 0, 0, 0);
            f32x4 d5 = __builtin_amdgcn_mfma_f32_16x16x16f16(a1s_1, b1s1, zero, 0, 0, 0);
            f32x4 d6 = __builtin_amdgcn_mfma_f32_16x16x16f16(a1b_1, b1b0, zero, 0, 0, 0);
            f32x4 d7 = __builtin_amdgcn_mfma_f32_16x16x16f16(a1b_1, b1b1, zero, 0, 0, 0);

            // exp2 + cvt: C/D layout == A-operand layout of 16x16x16f16 (k=quad*4+r)
            half4 w0 = expcvt(d0), w1 = expcvt(d1), w2 = expcvt(d2), w3 = expcvt(d3);
            half4 w4 = expcvt(d4), w5 = expcvt(d5), w6 = expcvt(d6), w7 = expcvt(d7);

            // GEMM-2: out[i][c] += w[i][j] * p[c][j]
            as0 = __builtin_amdgcn_mfma_f32_16x16x16f16(w0, p2_0, as0, 0, 0, 0);
            as1 = __builtin_amdgcn_mfma_f32_16x16x16f16(w1, p2_0, as1, 0, 0, 0);
            ab0 = __builtin_amdgcn_mfma_f32_16x16x16f16(w2, p2_0, ab0, 0, 0, 0);
            ab1 = __builtin_amdgcn_mfma_f32_16x16x16f16(w3, p2_0, ab1, 0, 0, 0);
            as0 = __builtin_amdgcn_mfma_f32_16x16x16f16(w4, p2_1, as0, 0, 0, 0);
            as1 = __builtin_amdgcn_mfma_f32_16x16x16f16(w5, p2_1, as1, 0, 0, 0);
            ab0 = __builtin_amdgcn_mfma_f32_16x16x16f16(w6, p2_1, ab0, 0, 0, 0);
            ab1 = __builtin_amdgcn_mfma_f32_16x16x16f16(w7, p2_1, ab1, 0, 0, 0);
        }
        __syncthreads();
    }

    // writeout: plain stores to this j-split's private partial slice
    if (il < C) {
        float* psp = part + ((size_t)jc * 20 + il) * N;
        float* pbl = part + ((size_t)jc * 20 + C + il) * N;
        int ia = i0 + quad * 4;
#pragma unroll
        for (int r = 0; r < 4; ++r) {
            psp[ia + r]      = as0[r];
            psp[ia + 16 + r] = as1[r];
            pbl[ia + r]      = ab0[r];
            pbl[ia + 16 + r] = ab1[r];
        }
    }
}

extern "C" void kernel_launch(void* const* d_in, const int* in_sizes, int n_in,
                              void* d_out, int out_size, void* d_ws, size_t ws_size,
                              hipStream_t stream) {
    const float* unaries = (const float*)d_in[0];   // [10, 8192]
    const float* feat    = (const float*)d_in[1];   // [6, 8192]
    const float* SW      = (const float*)d_in[2];   // [10,10]
    const float* BW      = (const float*)d_in[3];   // [10,10]
    const float* CM      = (const float*)d_in[4];   // [10,10]
    float* out = (float*)d_out;

    char* ws = (char*)d_ws;
    half8* ajs    = (half8*)(ws + WS_AJS);
    half8* ajb    = (half8*)(ws + WS_AJB);
    _Float16* pf  = (_Float16*)(ws + WS_PF);
    float* part   = (float*)(ws + WS_PART);

    combine_kernel<<<N / CBLOCK, CBLOCK, 0, stream>>>(unaries, feat, SW, BW, CM, part,
                                                      pf, ajs, ajb, out, 0, 0);
    for (int it = 1; it <= NUM_ITERS; ++it) {
        filter_kernel<<<dim3(NIB, JCH), FBLOCK, 0, stream>>>(feat, (const half4*)ajs,
                                                             (const half4*)ajb, pf, part);
        combine_kernel<<<N / CBLOCK, CBLOCK, 0, stream>>>(unaries, feat, SW, BW, CM, part,
                                                          pf, ajs, ajb, out,
                                                          1, it == NUM_ITERS ? 1 : 0);
    }
}

// Round 7
// 201.649 us; speedup vs baseline: 1.8914x; 1.8914x over previous
//
#include <hip/hip_runtime.h>
#include <math.h>

#define N 8192
#define C 10
#define NUM_ITERS 5
#define FBLOCK 256        /* filter block: 4 waves */
#define JCH 8             /* j splits (partial accumulators) */
#define JPB (N / JCH)     /* 1024 j's per block */
#define JT 512            /* j's staged per LDS chunk */
#define IBLK 128          /* i's per filter block: 4 waves x 32 */
#define NIB (N / IBLK)    /* 64 */
#define LOG2E 1.44269504088896340736f
#define C3 (LOG2E / 64.0f)
#define PROW (JT + 8)     /* padded LDS row for p (f16 elems) */

typedef _Float16 half8 __attribute__((ext_vector_type(8)));
typedef _Float16 half4 __attribute__((ext_vector_type(4)));
typedef float f32x4 __attribute__((ext_vector_type(4)));

// ws byte offsets:
//   ajs half8[N] : j-side spatial aug features   [f*C3 x3, 0, 0,0,-h3*C3, 1]
//   ajb half8[N] : j-side bilateral aug features [f*L2E x6, -h6*L2E, 1]
//   pf  f16[16][N] : softmax probs, rows 10..15 zero
//   part float[JCH][20][N] : per-j-split partials
//   red  float[20][N] : reduced partials
#define WS_AJS 0
#define WS_AJB (N * 16)
#define WS_PF  (N * 32)
#define WS_PART (N * 64)
#define WS_RED (N * 64 + (size_t)JCH * 20 * N * 4)

// once per launch: prep augmented features + softmax(unaries) -> pf
__global__ __launch_bounds__(256) void init_kernel(
    const float* __restrict__ unaries, const float* __restrict__ feat,
    half8* __restrict__ ajs, half8* __restrict__ ajb, _Float16* __restrict__ pf) {
    int n = blockIdx.x * 256 + threadIdx.x;
    float f[6];
#pragma unroll
    for (int d = 0; d < 6; ++d) f[d] = feat[d * N + n];
    float h3 = 0.5f * (f[0] * f[0] + f[1] * f[1] + f[2] * f[2]);
    float h6 = h3 + 0.5f * (f[3] * f[3] + f[4] * f[4] + f[5] * f[5]);
    half8 a = {};
    a[0] = (_Float16)(f[0] * C3);
    a[1] = (_Float16)(f[1] * C3);
    a[2] = (_Float16)(f[2] * C3);
    a[6] = (_Float16)(-h3 * C3);
    a[7] = (_Float16)1.0f;
    ajs[n] = a;
    half8 b;
#pragma unroll
    for (int d = 0; d < 6; ++d) b[d] = (_Float16)(f[d] * LOG2E);
    b[6] = (_Float16)(-h6 * LOG2E);
    b[7] = (_Float16)1.0f;
    ajb[n] = b;

    float q[C];
#pragma unroll
    for (int c = 0; c < C; ++c) q[c] = unaries[c * N + n];
    float m = q[0];
#pragma unroll
    for (int c = 1; c < C; ++c) m = fmaxf(m, q[c]);
    float e[C], s = 0.0f;
#pragma unroll
    for (int c = 0; c < C; ++c) {
        e[c] = __builtin_amdgcn_exp2f((q[c] - m) * LOG2E);
        s += e[c];
    }
    float inv = 1.0f / s;
#pragma unroll
    for (int c = 0; c < C; ++c) pf[c * N + n] = (_Float16)(e[c] * inv);
#pragma unroll
    for (int c = C; c < 16; ++c) pf[c * N + n] = (_Float16)0.0f;
}

// red[20][N] = sum_jc part[jc][20][N]  (pure float4 streaming, high MLP)
__global__ __launch_bounds__(256) void reduce_kernel(const float4* __restrict__ part,
                                                     float4* __restrict__ red) {
    int o = blockIdx.x * 256 + threadIdx.x;   // float4 index into [20][N/4]
    float4 v0 = part[o];
    float4 v1 = part[1 * 20 * (N / 4) + o];
    float4 v2 = part[2 * 20 * (N / 4) + o];
    float4 v3 = part[3 * 20 * (N / 4) + o];
    float4 v4 = part[4 * 20 * (N / 4) + o];
    float4 v5 = part[5 * 20 * (N / 4) + o];
    float4 v6 = part[6 * 20 * (N / 4) + o];
    float4 v7 = part[7 * 20 * (N / 4) + o];
    float4 r;
    r.x = ((v0.x + v1.x) + (v2.x + v3.x)) + ((v4.x + v5.x) + (v6.x + v7.x));
    r.y = ((v0.y + v1.y) + (v2.y + v3.y)) + ((v4.y + v5.y) + (v6.y + v7.y));
    r.z = ((v0.z + v1.z) + (v2.z + v3.z)) + ((v4.z + v5.z) + (v6.z + v7.z));
    r.w = ((v0.w + v1.w) + (v2.w + v3.w)) + ((v4.w + v5.w) + (v6.w + v7.w));
    red[o] = r;
}

// message passing + compatibility + softmax (or final out). Helper-split loads:
// block=256 covers 128 n's; half h0 loads sp rows + unaries 0-4, h1 bl rows + 5-9.
__global__ __launch_bounds__(256) void combine_kernel(
    const float* __restrict__ unaries, const float* __restrict__ SW,
    const float* __restrict__ BW, const float* __restrict__ CM,
    const float* __restrict__ red, _Float16* __restrict__ pf,
    float* __restrict__ out, int is_last) {
    __shared__ float sSW[100], sBW[100], sCM[100];
    __shared__ float spl[10][128], bll[10][128], ul[10][128];
    int t = threadIdx.x;
    if (t < 100) { sSW[t] = SW[t]; sBW[t] = BW[t]; sCM[t] = CM[t]; }
    int nl = t & 127;
    int h = t >> 7;
    int n = blockIdx.x * 128 + nl;

    if (h == 0) {
#pragma unroll
        for (int k = 0; k < C; ++k) spl[k][nl] = red[k * N + n];
#pragma unroll
        for (int k = 0; k < 5; ++k) ul[k][nl] = unaries[k * N + n];
    } else {
#pragma unroll
        for (int k = 0; k < C; ++k) bll[k][nl] = red[(C + k) * N + n];
#pragma unroll
        for (int k = 5; k < C; ++k) ul[k][nl] = unaries[k * N + n];
    }
    __syncthreads();

    float q[C];
#pragma unroll
    for (int c = 0; c < C; ++c) {
        float m = 0.0f;
#pragma unroll
        for (int k = 0; k < C; ++k)
            m += sSW[c * C + k] * spl[k][nl] + sBW[c * C + k] * bll[k][nl];
        q[c] = m;   // msg
    }
    float qq[C];
#pragma unroll
    for (int c = 0; c < C; ++c) {
        float pw = 0.0f;
#pragma unroll
        for (int k = 0; k < C; ++k) pw += sCM[c * C + k] * q[k];
        qq[c] = ul[c][nl] - pw;
    }

    if (is_last) {
        // split final store: h0 writes c 0..4, h1 writes c 5..9
#pragma unroll
        for (int c = 0; c < 5; ++c) out[(h * 5 + c) * N + n] = qq[h * 5 + c];
    } else {
        float m = qq[0];
#pragma unroll
        for (int c = 1; c < C; ++c) m = fmaxf(m, qq[c]);
        float e[C], s = 0.0f;
#pragma unroll
        for (int c = 0; c < C; ++c) {
            e[c] = __builtin_amdgcn_exp2f((qq[c] - m) * LOG2E);
            s += e[c];
        }
        float inv = 1.0f / s;
        // split pf stores: h0 writes rows 0..7, h1 rows 8..15 (10..15 zero)
#pragma unroll
        for (int c = 0; c < 8; ++c) {
            int row = h * 8 + c;
            float v = (row < C) ? e[row] * inv : 0.0f;
            pf[row * N + n] = (_Float16)v;
        }
    }
}

static __device__ inline half4 expcvt(f32x4 d) {
    half4 r;
    r[0] = (_Float16)__builtin_amdgcn_exp2f(d[0]);
    r[1] = (_Float16)__builtin_amdgcn_exp2f(d[1]);
    r[2] = (_Float16)__builtin_amdgcn_exp2f(d[2]);
    r[3] = (_Float16)__builtin_amdgcn_exp2f(d[3]);
    return r;
}

__global__ __launch_bounds__(FBLOCK, 4) void filter_kernel(
    const float* __restrict__ feat, const half4* __restrict__ ajs,
    const half4* __restrict__ ajb, const _Float16* __restrict__ pf,
    float* __restrict__ part) {
    __shared__ half4 ajs_l[JT * 2];        //  8 KB  [j][h]
    __shared__ half4 ajb_l[JT * 2];        //  8 KB
    __shared__ _Float16 p_l[16 * PROW];    // 16.25 KB

    int t = threadIdx.x;
    int ibb = blockIdx.x * IBLK;
    int jc = blockIdx.y;

    int lane = t & 63;
    int w = t >> 6;
    int il = lane & 15;
    int quad = lane >> 4;
    int h = quad & 1;
    bool klo = (quad < 2);
    int i0 = ibb + w * 32;   // wave's 32 i's: subtile0 = i0.., subtile1 = i0+16..

    const half4 hz = {};

    // B1 fragments (i-side aug), K=16 layout: lane holds B[k=quad*4+r][n=il]
    half4 b1s0, b1s1, b1b0, b1b1;
#pragma unroll
    for (int s = 0; s < 2; ++s) {
        int i = i0 + s * 16 + il;
        float g0 = feat[0 * N + i], g1 = feat[1 * N + i], g2 = feat[2 * N + i];
        float g3 = feat[3 * N + i], g4 = feat[4 * N + i], g5 = feat[5 * N + i];
        float h3 = 0.5f * (g0 * g0 + g1 * g1 + g2 * g2);
        float h6 = h3 + 0.5f * (g3 * g3 + g4 * g4 + g5 * g5);
        half4 slo = {(_Float16)g0, (_Float16)g1, (_Float16)g2, (_Float16)0.0f};
        half4 shi = {(_Float16)0.0f, (_Float16)0.0f, (_Float16)1.0f, (_Float16)(-h3 * C3)};
        half4 blo = {(_Float16)g0, (_Float16)g1, (_Float16)g2, (_Float16)g3};
        half4 bhi = {(_Float16)g4, (_Float16)g5, (_Float16)1.0f, (_Float16)(-h6 * LOG2E)};
        half4 vs = klo ? (h ? shi : slo) : hz;
        half4 vb = klo ? (h ? bhi : blo) : hz;
        if (s == 0) { b1s0 = vs; b1b0 = vb; } else { b1s1 = vs; b1b1 = vb; }
    }

    f32x4 as0 = {0.f, 0.f, 0.f, 0.f}, as1 = {0.f, 0.f, 0.f, 0.f};
    f32x4 ab0 = {0.f, 0.f, 0.f, 0.f}, ab1 = {0.f, 0.f, 0.f, 0.f};
    const f32x4 zero = {0.f, 0.f, 0.f, 0.f};

    for (int ch = 0; ch < JPB / JT; ++ch) {
        int jbase = jc * JPB + ch * JT;
        // ---- stage j-chunk (coalesced float4) ----
        {
            const float4* s0 = (const float4*)(ajs + (size_t)jbase * 2);
            const float4* s1 = (const float4*)(ajb + (size_t)jbase * 2);
            float4* d0 = (float4*)ajs_l;
            float4* d1 = (float4*)ajb_l;
            for (int k = t; k < JT; k += FBLOCK) { d0[k] = s0[k]; d1[k] = s1[k]; }
            const float4* ps = (const float4*)pf;
            float4* pd = (float4*)p_l;
            for (int k = t; k < 16 * (JT / 8); k += FBLOCK) {
                int c = k >> 6, off = k & 63;
                pd[c * (PROW / 8) + off] = ps[c * (N / 8) + (jbase >> 3) + off];
            }
        }
        __syncthreads();

#pragma unroll 2
        for (int jb = 0; jb < JT; jb += 32) {
            int j0 = jb, j1 = jb + 16;
            // hoisted LDS reads (both groups) so latency overlaps
            half4 vs0 = ajs_l[(j0 + il) * 2 + h];
            half4 vb0 = ajb_l[(j0 + il) * 2 + h];
            half4 vs1 = ajs_l[(j1 + il) * 2 + h];
            half4 vb1 = ajb_l[(j1 + il) * 2 + h];
            half4 p2_0 = *(const half4*)&p_l[il * PROW + j0 + quad * 4];
            half4 p2_1 = *(const half4*)&p_l[il * PROW + j1 + quad * 4];
            half4 a1s_0 = klo ? vs0 : hz;
            half4 a1b_0 = klo ? vb0 : hz;
            half4 a1s_1 = klo ? vs1 : hz;
            half4 a1b_1 = klo ? vb1 : hz;

            // GEMM-1: S^T[j][i] in C/D layout (8 independent chains)
            f32x4 d0 = __builtin_amdgcn_mfma_f32_16x16x16f16(a1s_0, b1s0, zero, 0, 0, 0);
            f32x4 d1 = __builtin_amdgcn_mfma_f32_16x16x16f16(a1s_0, b1s1, zero, 0, 0, 0);
            f32x4 d2 = __builtin_amdgcn_mfma_f32_16x16x16f16(a1b_0, b1b0, zero, 0, 0, 0);
            f32x4 d3 = __builtin_amdgcn_mfma_f32_16x16x16f16(a1b_0, b1b1, zero, 0, 0, 0);
            f32x4 d4 = __builtin_amdgcn_mfma_f32_16x16x16f16(a1s_1, b1s0, zero, 0, 0, 0);
            f32x4 d5 = __builtin_amdgcn_mfma_f32_16x16x16f16(a1s_1, b1s1, zero, 0, 0, 0);
            f32x4 d6 = __builtin_amdgcn_mfma_f32_16x16x16f16(a1b_1, b1b0, zero, 0, 0, 0);
            f32x4 d7 = __builtin_amdgcn_mfma_f32_16x16x16f16(a1b_1, b1b1, zero, 0, 0, 0);

            // exp2 + cvt: C/D layout == A-operand layout of 16x16x16f16 (k=quad*4+r)
            half4 w0 = expcvt(d0), w1 = expcvt(d1), w2 = expcvt(d2), w3 = expcvt(d3);
            half4 w4 = expcvt(d4), w5 = expcvt(d5), w6 = expcvt(d6), w7 = expcvt(d7);

            // GEMM-2: out[i][c] += w[i][j] * p[c][j]
            as0 = __builtin_amdgcn_mfma_f32_16x16x16f16(w0, p2_0, as0, 0, 0, 0);
            as1 = __builtin_amdgcn_mfma_f32_16x16x16f16(w1, p2_0, as1, 0, 0, 0);
            ab0 = __builtin_amdgcn_mfma_f32_16x16x16f16(w2, p2_0, ab0, 0, 0, 0);
            ab1 = __builtin_amdgcn_mfma_f32_16x16x16f16(w3, p2_0, ab1, 0, 0, 0);
            as0 = __builtin_amdgcn_mfma_f32_16x16x16f16(w4, p2_1, as0, 0, 0, 0);
            as1 = __builtin_amdgcn_mfma_f32_16x16x16f16(w5, p2_1, as1, 0, 0, 0);
            ab0 = __builtin_amdgcn_mfma_f32_16x16x16f16(w6, p2_1, ab0, 0, 0, 0);
            ab1 = __builtin_amdgcn_mfma_f32_16x16x16f16(w7, p2_1, ab1, 0, 0, 0);
        }
        __syncthreads();
    }

    // writeout: plain stores to this j-split's private partial slice
    if (il < C) {
        float* psp = part + ((size_t)jc * 20 + il) * N;
        float* pbl = part + ((size_t)jc * 20 + C + il) * N;
        int ia = i0 + quad * 4;
#pragma unroll
        for (int r = 0; r < 4; ++r) {
            psp[ia + r]      = as0[r];
            psp[ia + 16 + r] = as1[r];
            pbl[ia + r]      = ab0[r];
            pbl[ia + 16 + r] = ab1[r];
        }
    }
}

extern "C" void kernel_launch(void* const* d_in, const int* in_sizes, int n_in,
                              void* d_out, int out_size, void* d_ws, size_t ws_size,
                              hipStream_t stream) {
    const float* unaries = (const float*)d_in[0];   // [10, 8192]
    const float* feat    = (const float*)d_in[1];   // [6, 8192]
    const float* SW      = (const float*)d_in[2];   // [10,10]
    const float* BW      = (const float*)d_in[3];   // [10,10]
    const float* CM      = (const float*)d_in[4];   // [10,10]
    float* out = (float*)d_out;

    char* ws = (char*)d_ws;
    half8* ajs    = (half8*)(ws + WS_AJS);
    half8* ajb    = (half8*)(ws + WS_AJB);
    _Float16* pf  = (_Float16*)(ws + WS_PF);
    float* part   = (float*)(ws + WS_PART);
    float* red    = (float*)(ws + WS_RED);

    init_kernel<<<N / 256, 256, 0, stream>>>(unaries, feat, ajs, ajb, pf);
    for (int it = 1; it <= NUM_ITERS; ++it) {
        filter_kernel<<<dim3(NIB, JCH), FBLOCK, 0, stream>>>(feat, (const half4*)ajs,
                                                             (const half4*)ajb, pf, part);
        reduce_kernel<<<20 * N / 4 / 256, 256, 0, stream>>>((const float4*)part,
                                                            (float4*)red);
        combine_kernel<<<N / 128, 256, 0, stream>>>(unaries, SW, BW, CM, red, pf, out,
                                                    it == NUM_ITERS ? 1 : 0);
    }
}